// Round 7
// baseline (272.143 us; speedup 1.0000x reference)
//
#include <hip/hip_runtime.h>
#include <math.h>

#define IN_F 512
#define OUTF 128
#define NEG_SLOPE 0.2f

// proj1 geometry: 4 waves/block, each wave owns a 128-wide K quarter of 64 rows
#define PROWS 64
#define TKQ 32                // k-depth staged per tile (per wave)
#define QTILES 4              // 128 / 32
#define PITCH 36              // floats per LDS row (measured 0 bank conflicts)

// bucketing geometry
#define NPB 128               // nodes per bucket (dst >> 7)
#define NBMAX 784             // >= ceil(100000/128) = 782
#define EPB 8192              // edges per binning block
#define SRCMASK 0x1FFFF       // 17-bit src (N < 131072)

// ---------------- prep: fold weights + zero bucketTotal ----------------
__global__ void k_prep(const float* __restrict__ fc1, const float* __restrict__ al1,
                       const float* __restrict__ ar1, const float* __restrict__ fc2,
                       const float* __restrict__ al2, const float* __restrict__ ar2,
                       float* __restrict__ wfold, float* __restrict__ w2al,
                       float* __restrict__ w2ar, int* __restrict__ bucketTotal) {
  int t = threadIdx.x;
  if (blockIdx.x == 0) {
    int k = t;  // 512 threads
#pragma unroll
    for (int h = 0; h < 4; ++h) {
      float wl = 0.f, wr = 0.f, wb = 0.f;
#pragma unroll
      for (int j = 0; j < 4; ++j) {
        float wv = fc1[k * 16 + h * 4 + j];
        wl = fmaf(wv, al1[h * 4 + j], wl);
        wr = fmaf(wv, ar1[h * 4 + j], wr);
        wb += wv;
      }
      wfold[k * 12 + h] = wl;
      wfold[k * 12 + 4 + h] = wr;
      wfold[k * 12 + 8 + h] = 0.25f * wb;
    }
  } else {
    if (t < 8) {
      int h = t >> 1;
      const float* a = (t & 1) ? ar2 : al2;
      float s = 0.f;
#pragma unroll 16
      for (int c = 0; c < OUTF; ++c) s += fc2[h * OUTF + c] * a[c];
      if (t & 1) w2ar[h] = s; else w2al[h] = s;
    }
    for (int i = t; i < NBMAX; i += 512) bucketTotal[i] = 0;
  }
}

// ---------------- layer 1 projection ----------------
// wave w handles K quarter w for 64 rows; readfirstlane forces the quarter index
// scalar so weight addresses stay wave-uniform -> s_load path.
__global__ __launch_bounds__(256) void k_proj1(
    const float* __restrict__ x, const float* __restrict__ wf,
    float* __restrict__ el1, float* __restrict__ er1, float* __restrict__ hb1, int n)
{
  __shared__ float xs[4 * PROWS * PITCH];       // 36 KB, wave-private quarters
  const int t = threadIdx.x;
  const int lane = t & 63;
  const int kq = __builtin_amdgcn_readfirstlane(t >> 6);   // SGPR
  const int rowBase = blockIdx.x * PROWS;
  const int myRow = rowBase + lane;
  const int kBase = kq * (IN_F / 4);
  float* xw = xs + kq * (PROWS * PITCH);
  float acc[12];
#pragma unroll
  for (int c = 0; c < 12; ++c) acc[c] = 0.f;

  float4 st[8];
#pragma unroll
  for (int i = 0; i < 8; ++i) {                 // prefetch tile 0
    int f4 = lane + i * 64;
    int rr = f4 >> 3, c4 = (f4 & 7) << 2;
    int row = rowBase + rr;
    st[i] = (row < n) ? *(const float4*)&x[(size_t)row * IN_F + kBase + c4]
                      : make_float4(0.f, 0.f, 0.f, 0.f);
  }

  for (int tile = 0; tile < QTILES; ++tile) {
    __syncthreads();
#pragma unroll
    for (int i = 0; i < 8; ++i) {
      int f4 = lane + i * 64;
      int rr = f4 >> 3, c4 = (f4 & 7) << 2;
      *(float4*)&xw[rr * PITCH + c4] = st[i];
    }
    if (tile + 1 < QTILES) {
      int k0 = kBase + (tile + 1) * TKQ;
#pragma unroll
      for (int i = 0; i < 8; ++i) {
        int f4 = lane + i * 64;
        int rr = f4 >> 3, c4 = (f4 & 7) << 2;
        int row = rowBase + rr;
        st[i] = (row < n) ? *(const float4*)&x[(size_t)row * IN_F + k0 + c4]
                          : make_float4(0.f, 0.f, 0.f, 0.f);
      }
    }
    __syncthreads();
    const float* __restrict__ wk0 = wf + (size_t)(kBase + tile * TKQ) * 12;
#pragma unroll
    for (int kk = 0; kk < 8; ++kk) {
      float4 xv = *(const float4*)&xw[lane * PITCH + kk * 4];
      float xj[4] = {xv.x, xv.y, xv.z, xv.w};
#pragma unroll
      for (int j = 0; j < 4; ++j) {
        const float* __restrict__ wkk = wk0 + (kk * 4 + j) * 12;  // uniform -> s_load
#pragma unroll
        for (int c = 0; c < 12; ++c)
          acc[c] = fmaf(xj[j], wkk[c], acc[c]);
      }
    }
  }

  // cross-wave reduce: waves 1..3 dump partials, wave 0 sums + writes
  __syncthreads();
  if (kq > 0) {
    float* rr = xs + ((kq - 1) * PROWS + lane) * 12;
#pragma unroll
    for (int c = 0; c < 12; ++c) rr[c] = acc[c];
  }
  __syncthreads();
  if (kq == 0 && myRow < n) {
#pragma unroll
    for (int w = 0; w < 3; ++w) {
      const float* rr = xs + ((w * PROWS) + lane) * 12;
#pragma unroll
      for (int c = 0; c < 12; ++c) acc[c] += rr[c];
    }
    *(float4*)&el1[(size_t)myRow * 4] = make_float4(acc[0], acc[1], acc[2], acc[3]);
    *(float4*)&er1[(size_t)myRow * 4] = make_float4(acc[4], acc[5], acc[6], acc[7]);
    *(float4*)&hb1[(size_t)myRow * 4] = make_float4(acc[8], acc[9], acc[10], acc[11]);
  }
}

// ---------------- bucket histogram ----------------
__global__ __launch_bounds__(256) void k_bhist(const int* __restrict__ dst,
                                               int* __restrict__ bucketTotal, int e) {
  __shared__ int hist[NBMAX];
  int t = threadIdx.x;
  for (int i = t; i < NBMAX; i += 256) hist[i] = 0;
  __syncthreads();
  int base = blockIdx.x * EPB;
#pragma unroll
  for (int i = 0; i < EPB / 256; ++i) {
    int idx = base + t + i * 256;
    if (idx < e) atomicAdd(&hist[dst[idx] >> 7], 1);
  }
  __syncthreads();
  for (int i = t; i < NBMAX; i += 256)
    if (hist[i] > 0) atomicAdd(&bucketTotal[i], hist[i]);
}

// ---------------- bucket scan (1 block, VT=4) ----------------
__global__ __launch_bounds__(256) void k_bscan(const int* __restrict__ bucketTotal,
                                               int* __restrict__ bucketBase,
                                               int* __restrict__ bucketCursor,
                                               int nb, int e) {
  __shared__ int sums[256];
  int t = threadIdx.x;
  int v[4];
  int s = 0;
#pragma unroll
  for (int j = 0; j < 4; ++j) {
    int id = t * 4 + j;
    int d = (id < nb) ? bucketTotal[id] : 0;
    v[j] = s; s += d;
  }
  sums[t] = s;
  __syncthreads();
  for (int off = 1; off < 256; off <<= 1) {
    int u = (t >= off) ? sums[t - off] : 0;
    __syncthreads();
    sums[t] += u;
    __syncthreads();
  }
  int excl = sums[t] - s;
#pragma unroll
  for (int j = 0; j < 4; ++j) {
    int id = t * 4 + j;
    if (id < nb) { bucketBase[id] = excl + v[j]; bucketCursor[id] = excl + v[j]; }
    if (id == nb) bucketBase[id] = e;
  }
}

// ---------------- binned scatter: block-aggregated reservation ----------------
__global__ __launch_bounds__(256) void k_bscat(const int* __restrict__ src,
                                               const int* __restrict__ dst,
                                               int* __restrict__ bucketCursor,
                                               unsigned* __restrict__ ep, int e) {
  __shared__ int hist[NBMAX];
  __shared__ int base[NBMAX];
  __shared__ int lcur[NBMAX];
  int t = threadIdx.x;
  for (int i = t; i < NBMAX; i += 256) hist[i] = 0;
  __syncthreads();
  int blockBase = blockIdx.x * EPB;
#pragma unroll
  for (int i = 0; i < EPB / 256; ++i) {
    int idx = blockBase + t + i * 256;
    if (idx < e) atomicAdd(&hist[dst[idx] >> 7], 1);
  }
  __syncthreads();
  for (int i = t; i < NBMAX; i += 256) {
    if (hist[i] > 0) base[i] = atomicAdd(&bucketCursor[i], hist[i]);
    lcur[i] = 0;
  }
  __syncthreads();
#pragma unroll
  for (int i = 0; i < EPB / 256; ++i) {
    int idx = blockBase + t + i * 256;
    if (idx < e) {
      int d = dst[idx];
      int b = d >> 7;
      int p = base[b] + atomicAdd(&lcur[b], 1);
      ep[p] = (unsigned)src[idx] | ((unsigned)(d & (NPB - 1)) << 17);
    }
  }
}

// ---------------- layer 1 bucket aggregation + node epilogue ----------------
__global__ __launch_bounds__(256) void k_bagg1(
    const unsigned* __restrict__ ep, const int* __restrict__ bucketBase,
    const float* __restrict__ el1, const float* __restrict__ er1,
    const float* __restrict__ hb1, const float* __restrict__ bias1,
    const float* __restrict__ w2al, const float* __restrict__ w2ar,
    float* __restrict__ h2in, float* __restrict__ el2, float* __restrict__ er2, int n)
{
  __shared__ float acc[NPB * 8];   // per node: den[4], num[4]
  __shared__ float ers[NPB * 4];
  int t = threadIdx.x;
  int b = blockIdx.x;
  int nodeBase = b * NPB;
  for (int i = t; i < NPB * 8; i += 256) acc[i] = 0.f;
  for (int i = t; i < NPB; i += 256) {
    int node = nodeBase + i;
    float4 v = (node < n) ? *(const float4*)&er1[(size_t)node * 4]
                          : make_float4(0.f, 0.f, 0.f, 0.f);
    *(float4*)&ers[i * 4] = v;
  }
  __syncthreads();
  int beg = bucketBase[b], end = bucketBase[b + 1];
  for (int j = beg + t; j < end; j += 256) {
    unsigned p = ep[j];
    int s = p & SRCMASK;
    int dl = p >> 17;
    float4 el = *(const float4*)&el1[(size_t)s * 4];
    float4 hb = *(const float4*)&hb1[(size_t)s * 4];
    float* a = &acc[dl * 8];
    float eh, w;
    eh = el.x + ers[dl*4+0]; eh = (eh > 0.f) ? eh : NEG_SLOPE * eh; w = __expf(eh);
    atomicAdd(&a[0], w); atomicAdd(&a[4], w * hb.x);
    eh = el.y + ers[dl*4+1]; eh = (eh > 0.f) ? eh : NEG_SLOPE * eh; w = __expf(eh);
    atomicAdd(&a[1], w); atomicAdd(&a[5], w * hb.y);
    eh = el.z + ers[dl*4+2]; eh = (eh > 0.f) ? eh : NEG_SLOPE * eh; w = __expf(eh);
    atomicAdd(&a[2], w); atomicAdd(&a[6], w * hb.z);
    eh = el.w + ers[dl*4+3]; eh = (eh > 0.f) ? eh : NEG_SLOPE * eh; w = __expf(eh);
    atomicAdd(&a[3], w); atomicAdd(&a[7], w * hb.w);
  }
  __syncthreads();
  float mb[4], wl[4], wr[4];
#pragma unroll
  for (int h = 0; h < 4; ++h) {
    mb[h] = 0.25f * (bias1[h*4] + bias1[h*4+1] + bias1[h*4+2] + bias1[h*4+3]);
    wl[h] = w2al[h]; wr[h] = w2ar[h];
  }
  for (int i = t; i < NPB; i += 256) {
    int node = nodeBase + i;
    if (node >= n) continue;
    float pl = 0.f, pr = 0.f, v[4];
#pragma unroll
    for (int h = 0; h < 4; ++h) {
      float den = acc[i * 8 + h];
      float num = acc[i * 8 + 4 + h];
      float vv = (den > 0.f) ? num / den : 0.f;
      vv += mb[h];
      vv = (vv > 0.f) ? vv : 0.f;
      v[h] = vv;
      pl = fmaf(vv, wl[h], pl);
      pr = fmaf(vv, wr[h], pr);
    }
    *(float4*)&h2in[(size_t)node * 4] = make_float4(v[0], v[1], v[2], v[3]);
    el2[node] = pl;
    er2[node] = pr;
  }
}

// ---------------- layer 2 bucket aggregation + fused output projection ----------------
__global__ __launch_bounds__(256) void k_bagg2(
    const unsigned* __restrict__ ep, const int* __restrict__ bucketBase,
    const float* __restrict__ el2, const float* __restrict__ er2,
    const float* __restrict__ h2in, const float* __restrict__ w2,
    const float* __restrict__ bias2, float* __restrict__ out, int n)
{
  __shared__ float acc[NPB * 5];   // per node: den, g[4]
  __shared__ float ers2[NPB];
  __shared__ float w2s[4 * OUTF];
  __shared__ float b2s[OUTF];
  int t = threadIdx.x;
  int b = blockIdx.x;
  int nodeBase = b * NPB;
  for (int i = t; i < NPB * 5; i += 256) acc[i] = 0.f;
  for (int i = t; i < NPB; i += 256) {
    int node = nodeBase + i;
    ers2[i] = (node < n) ? er2[node] : 0.f;
  }
  for (int i = t; i < 4 * OUTF; i += 256) w2s[i] = w2[i];
  if (t < OUTF) b2s[t] = bias2[t];
  __syncthreads();
  int beg = bucketBase[b], end = bucketBase[b + 1];
  for (int j = beg + t; j < end; j += 256) {
    unsigned p = ep[j];
    int s = p & SRCMASK;
    int dl = p >> 17;
    float eh = el2[s] + ers2[dl];
    eh = (eh > 0.f) ? eh : NEG_SLOPE * eh;
    float w = __expf(eh);
    float4 hv = *(const float4*)&h2in[(size_t)s * 4];
    float* a = &acc[dl * 5];
    atomicAdd(&a[0], w);
    atomicAdd(&a[1], w * hv.x);
    atomicAdd(&a[2], w * hv.y);
    atomicAdd(&a[3], w * hv.z);
    atomicAdd(&a[4], w * hv.w);
  }
  __syncthreads();
  for (int idx = t; idx < NPB * (OUTF / 2); idx += 256) {
    int i = idx >> 6;
    int node = nodeBase + i;
    if (node >= n) continue;
    int c = (idx & 63) * 2;
    float den = acc[i * 5];
    float inv = (den > 0.f) ? 1.0f / den : 0.f;
    float gx = acc[i*5+1] * inv, gy = acc[i*5+2] * inv;
    float gz = acc[i*5+3] * inv, gw = acc[i*5+4] * inv;
    float2 o;
    o.x = gx*w2s[c]   + gy*w2s[OUTF+c]   + gz*w2s[2*OUTF+c]   + gw*w2s[3*OUTF+c]   + b2s[c];
    o.y = gx*w2s[c+1] + gy*w2s[OUTF+c+1] + gz*w2s[2*OUTF+c+1] + gw*w2s[3*OUTF+c+1] + b2s[c+1];
    *(float2*)&out[(size_t)node * OUTF + c] = o;
  }
}

// ---------------- launch ----------------
extern "C" void kernel_launch(void* const* d_in, const int* in_sizes, int n_in,
                              void* d_out, int out_size, void* d_ws, size_t ws_size,
                              hipStream_t stream) {
  const float* nfeats = (const float*)d_in[0];
  const int*   srcp   = (const int*)d_in[2];
  const int*   dstp   = (const int*)d_in[3];
  const float* fc1    = (const float*)d_in[4];
  const float* al1    = (const float*)d_in[5];
  const float* ar1    = (const float*)d_in[6];
  const float* bias1  = (const float*)d_in[7];
  const float* fc2    = (const float*)d_in[8];
  const float* al2    = (const float*)d_in[9];
  const float* ar2    = (const float*)d_in[10];
  const float* bias2  = (const float*)d_in[11];

  const int N = in_sizes[0] / IN_F;     // 100000
  const int E = in_sizes[2];            // 1600000
  const int NB = (N + NPB - 1) / NPB;   // 782

  float* ws   = (float*)d_ws;
  float* el1  = ws;                          // 4N
  float* er1  = el1 + (size_t)4 * N;         // 4N
  float* hb1  = er1 + (size_t)4 * N;         // 4N
  float* h2in = hb1 + (size_t)4 * N;         // 4N
  float* el2  = h2in + (size_t)4 * N;        // N
  float* er2  = el2 + N;                     // N
  float* wfold= er2 + N;                     // 512*12
  float* w2al = wfold + 512 * 12;            // 4
  float* w2ar = w2al + 4;                    // 4
  int* bucketTotal  = (int*)(w2ar + 4);      // NBMAX
  int* bucketBase   = bucketTotal + NBMAX;   // NBMAX+1
  int* bucketCursor = bucketBase + NBMAX + 1;// NBMAX
  unsigned* ep      = (unsigned*)(bucketCursor + NBMAX);  // E

  const int binBlocks = (E + EPB - 1) / EPB;       // 196
  const int projBlocks = (N + PROWS - 1) / PROWS;  // 1563

  k_prep<<<2, 512, 0, stream>>>(fc1, al1, ar1, fc2, al2, ar2,
                                wfold, w2al, w2ar, bucketTotal);
  k_bhist<<<binBlocks, 256, 0, stream>>>(dstp, bucketTotal, E);
  k_proj1<<<projBlocks, 256, 0, stream>>>(nfeats, wfold, el1, er1, hb1, N);
  k_bscan<<<1, 256, 0, stream>>>(bucketTotal, bucketBase, bucketCursor, NB, E);
  k_bscat<<<binBlocks, 256, 0, stream>>>(srcp, dstp, bucketCursor, ep, E);
  k_bagg1<<<NB, 256, 0, stream>>>(ep, bucketBase, el1, er1, hb1, bias1,
                                  w2al, w2ar, h2in, el2, er2, N);
  k_bagg2<<<NB, 256, 0, stream>>>(ep, bucketBase, el2, er2, h2in,
                                  fc2, bias2, (float*)d_out, N);
}